// Round 6
// baseline (365.008 us; speedup 1.0000x reference)
//
#include <hip/hip_runtime.h>
#include <hip/hip_bf16.h>

#define T_   16
#define B_   32
#define C_   256
#define HW_  256
#define TP_  12                    // T - K
#define NE_  (B_*C_*HW_)           // 2097152 elements per t-slice
#define NOUT0 (T_*NE_)             // 33554432 (spk passthrough, fp32)

typedef __attribute__((ext_vector_type(8))) short short8;   // 8 bf16 = 4 VGPRs
typedef __attribute__((ext_vector_type(4))) float f32x4;    // clang ext-vector

// ---- ws layout (bytes) ----
// [0, 131072)            : Wb bf16 (256*256)
// [131072, +3145728)     : ctx bits: [t'<12][b][c][8 words] uint32
// [3276800, +4194304)    : spk bits: [t<16][b][c][8 words] uint32
// [7471104, +1536)       : s_pos[384], s_neg[384] f32 accumulators
// NOTE hw bit-order inside the 8 words is PERMUTED (bit i of word-pair j
// means hw=4i+j); consistent between spkw and ctxw, and k_gemm only ever
// pairs equal (word,bit) coords of the two, so the permutation cancels.
#define WS_WB   0
#define WS_CTX  131072
#define WS_SPK  3276800
#define WS_ACC  7471104

// ---------------- setup: W fp32 -> bf16, zero accumulators ----------------
__global__ void k_setup(const float* __restrict__ W,
                        unsigned short* __restrict__ Wb,
                        float* __restrict__ acc) {
    int i = blockIdx.x*256 + threadIdx.x;         // 256 blocks -> 65536
    __hip_bfloat16 h = __float2bfloat16(W[i]);
    Wb[i] = *(unsigned short*)&h;
    if (i < 768) acc[i] = 0.f;
}

// ---------------- scan: float4 passthrough + LIF scan + bit-pack ---------
// One wave = one (b,c) row (256 hw). Thread owns float4 = hw 4*lane..+3.
__global__ void k_scan(const f32x4* __restrict__ spk,
                       f32x4* __restrict__ out,
                       unsigned* __restrict__ ctxw,
                       unsigned* __restrict__ spkw) {
    int wave = (blockIdx.x*256 + threadIdx.x) >> 6;   // row id 0..8191 (=b*256+c)
    int lane = threadIdx.x & 63;
    long base = (long)wave*64 + lane;                 // float4 index
    float m0=0.f, m1=0.f, m2=0.f, m3=0.f;
    #pragma unroll
    for (int t = 0; t < T_; ++t) {
        long o = (long)t*(NE_/4) + base;
        f32x4 v = __builtin_nontemporal_load(&spk[o]);
        __builtin_nontemporal_store(v, &out[o]);      // exact passthrough
        if (t >= 4) {   // spk bits only needed for t in [4,16)
            unsigned long long s0 = __ballot(v.x != 0.f);
            unsigned long long s1 = __ballot(v.y != 0.f);
            unsigned long long s2 = __ballot(v.z != 0.f);
            unsigned long long s3 = __ballot(v.w != 0.f);
            if (lane < 8) {
                unsigned long long m = (lane<2)?s0 : (lane<4)?s1 : (lane<6)?s2 : s3;
                unsigned w = (lane & 1) ? (unsigned)(m>>32) : (unsigned)m;
                spkw[((long)t*8192 + wave)*8 + lane] = w;
            }
        }
        float r0 = (m0-1.f>0.f)?1.f:0.f; m0 = 0.5f*m0 + v.x - r0;
        float r1 = (m1-1.f>0.f)?1.f:0.f; m1 = 0.5f*m1 + v.y - r1;
        float r2 = (m2-1.f>0.f)?1.f:0.f; m2 = 0.5f*m2 + v.z - r2;
        float r3 = (m3-1.f>0.f)?1.f:0.f; m3 = 0.5f*m3 + v.w - r3;
        if (t < TP_) {
            unsigned long long c0 = __ballot(m0-1.f>0.f);
            unsigned long long c1 = __ballot(m1-1.f>0.f);
            unsigned long long c2 = __ballot(m2-1.f>0.f);
            unsigned long long c3 = __ballot(m3-1.f>0.f);
            if (lane >= 8 && lane < 16) {
                int j = lane - 8;
                unsigned long long m = (j<2)?c0 : (j<4)?c1 : (j<6)?c2 : c3;
                unsigned w = (j & 1) ? (unsigned)(m>>32) : (unsigned)m;
                ctxw[((long)t*8192 + wave)*8 + j] = w;
            }
        }
    }
}

// ---------------- gemm: X = W @ S per (t,b,hwtile); mask-reduce vs ctx ----
// S comes bit-packed; expand to bf16 in LDS once, then barrier-free K loop.
__global__ __launch_bounds__(256, 2)
void k_gemm(const unsigned short* __restrict__ Wb,   // bf16 weight (o,c), in ws
            const unsigned* __restrict__ spkw,       // packed S bits
            const unsigned* __restrict__ ctxw,
            const int* __restrict__ ridx,
            float* __restrict__ spos, float* __restrict__ sneg) {
    int blk  = blockIdx.x;
    int pair = blk >> 2;                 // 0..383
    int jblk = blk & 3;
    int t  = 4 + (pair >> 5);            // 4..15
    int b  = pair & 31;
    int tp = t - 4;
    int hwbase = jblk * 64;

    int wv   = threadIdx.x >> 6;         // wave 0..3 -> o in [64*wv, 64*wv+64)
    int lane = threadIdx.x & 63;
    int quad = lane >> 4;
    int n    = lane & 15;

    // full S tile transposed: [hw 64][c 256+8pad] bf16 (rows 16B-aligned)
    __shared__ __align__(16) unsigned short Ssl[64*264];
    __shared__ __align__(16) unsigned Sw2[512];       // [wi 2][c 256]
    __shared__ unsigned ctxp[512], ctxn[512];
    __shared__ float red[8];

    // ---- load packed words + ctx masks (overlapped, one barrier) ----
    {
        int c = threadIdx.x;             // 0..255
        const uint2 w = *(const uint2*)&spkw[((long)t*8192 + b*256 + c)*8 + (hwbase>>5)];
        Sw2[c]       = w.x;
        Sw2[256 + c] = w.y;
    }
    int bneg = 0;
    #pragma unroll
    for (int i = 0; i < 32; ++i) if (ridx[i] == b) bneg = i;  // permutation inverse
    for (int i = threadIdx.x; i < 512; i += 256) {
        int o = i >> 1, w = i & 1;
        int hwword = (hwbase >> 5) + w;
        ctxp[i] = ctxw[((tp*B_ + b   )*C_ + o)*8 + hwword];
        ctxn[i] = ctxw[((tp*B_ + bneg)*C_ + o)*8 + hwword];
    }
    __syncthreads();

    // ---- expand bits -> bf16 tile ----
    #pragma unroll
    for (int p = 0; p < 8; ++p) {
        int v  = threadIdx.x + p*256;
        int hw = v >> 5;                 // 0..63
        int c0 = (v & 31)*8;             // 0..248
        int wi = hw >> 5, bit = hw & 31;
        uint4 wa = *(const uint4*)&Sw2[wi*256 + c0];
        uint4 wb2 = *(const uint4*)&Sw2[wi*256 + c0 + 4];
        unsigned ww[8] = {wa.x, wa.y, wa.z, wa.w, wb2.x, wb2.y, wb2.z, wb2.w};
        short8 s;
        #pragma unroll
        for (int j = 0; j < 8; ++j)
            s[j] = (short)(((ww[j] >> bit) & 1u) ? 0x3F80 : 0);
        *(short8*)&Ssl[hw*264 + c0] = s;
    }
    __syncthreads();

    // ---- barrier-free K loop: 8 x (4 ds_read_b128 + 4 dwordx4 + 16 MFMA) ----
    f32x4 acc[4][4] = {};
    #pragma unroll
    for (int kc = 0; kc < 256; kc += 32) {
        short8 bfr[4], afr[4];
        #pragma unroll
        for (int jt = 0; jt < 4; ++jt)
            bfr[jt] = *(const short8*)&Ssl[(jt*16 + n)*264 + kc + quad*8];
        #pragma unroll
        for (int ot = 0; ot < 4; ++ot) {
            int o = wv*64 + ot*16 + n;
            afr[ot] = *(const short8*)&Wb[o*256 + kc + quad*8];  // L2-resident
        }
        #pragma unroll
        for (int ot = 0; ot < 4; ++ot)
            #pragma unroll
            for (int jt = 0; jt < 4; ++jt)
                acc[ot][jt] = __builtin_amdgcn_mfma_f32_16x16x32_bf16(
                                  afr[ot], bfr[jt], acc[ot][jt], 0, 0, 0);
    }

    // ---- masked reduction vs ctx bits ----
    float P = 0.f, Nn = 0.f;
    #pragma unroll
    for (int ot = 0; ot < 4; ++ot)
        #pragma unroll
        for (int jt = 0; jt < 4; ++jt) {
            int hwl = jt*16 + n;
            int w = hwl >> 5, bit = hwl & 31;
            #pragma unroll
            for (int r = 0; r < 4; ++r) {
                int o = wv*64 + ot*16 + quad*4 + r;   // C/D: row=quad*4+r, col=n
                float x = acc[ot][jt][r];
                if ((ctxp[o*2 + w] >> bit) & 1) P  += x;
                if ((ctxn[o*2 + w] >> bit) & 1) Nn += x;
            }
        }
    for (int off = 32; off; off >>= 1) {
        P  += __shfl_down(P,  off);
        Nn += __shfl_down(Nn, off);
    }
    if (lane == 0) { red[wv] = P; red[4 + wv] = Nn; }
    __syncthreads();
    if (threadIdx.x == 0)
        atomicAdd(&spos[tp*32 + b],    red[0]+red[1]+red[2]+red[3]);
    if (threadIdx.x == 1)
        atomicAdd(&sneg[tp*32 + bneg], red[4]+red[5]+red[6]+red[7]);
}

// ---------------- final: scores -> logs -> loss, write fp32 tail ---------
__global__ void k_final(const float* __restrict__ spos,
                        const float* __restrict__ sneg,
                        float* __restrict__ out) {
    __shared__ float lsp_s[384], sn_s[384], lsn_s[12];
    int tid = threadIdx.x;
    if (tid < 384) {
        float mp = spos[tid] * (1.f/65536.f);
        lsp_s[tid] = logf(expf(mp) + 1e-4f);
        float mn = sneg[tid] * (1.f/65536.f);
        sn_s[tid] = expf(mn) + 1e-4f;
    }
    __syncthreads();
    if (tid < 12) {
        float s = 0.f;
        for (int b = 0; b < 32; ++b) s += sn_s[tid*32 + b];
        float lsn = logf(s);
        lsn_s[tid] = lsn;
        out[NOUT0 + 1 + 384 + tid] = lsn;
    }
    __syncthreads();
    if (tid < 384) out[NOUT0 + 1 + tid] = lsp_s[tid];
    if (tid == 0) {
        float L = 0.f;
        for (int t = 0; t < 12; ++t)
            for (int b = 0; b < 32; ++b)
                L += lsn_s[t] - lsp_s[t*32 + b];
        out[NOUT0] = L * (1.f/384.f);
    }
}

extern "C" void kernel_launch(void* const* d_in, const int* in_sizes, int n_in,
                              void* d_out, int out_size, void* d_ws, size_t ws_size,
                              hipStream_t stream) {
    const float* spk  = (const float*)d_in[0];
    // d_in[1] (mem_rec) is unused by the reference
    const float* W    = (const float*)d_in[2];
    const int*   ridx = (const int*)d_in[3];
    float* out = (float*)d_out;

    char* ws = (char*)d_ws;
    unsigned short* Wb   = (unsigned short*)(ws + WS_WB);
    unsigned*       ctxw = (unsigned*)(ws + WS_CTX);
    unsigned*       spkw = (unsigned*)(ws + WS_SPK);
    float*          acc  = (float*)(ws + WS_ACC);
    float*          spos = acc;          // 384
    float*          sneg = acc + 384;    // 384

    k_setup<<<256, 256, 0, stream>>>(W, Wb, acc);
    k_scan <<<2048, 256, 0, stream>>>((const f32x4*)spk, (f32x4*)out, ctxw, spkw);
    k_gemm <<<1536, 256, 0, stream>>>(Wb, spkw, ctxw, ridx, spos, sneg);
    k_final<<<1, 384, 0, stream>>>(spos, sneg, out);
}

// Round 7
// 321.864 us; speedup vs baseline: 1.1340x; 1.1340x over previous
//
#include <hip/hip_runtime.h>
#include <hip/hip_bf16.h>

#define T_   16
#define B_   32
#define C_   256
#define HW_  256
#define TP_  12                    // T - K
#define NE_  (B_*C_*HW_)           // 2097152 elements per t-slice
#define NOUT0 (T_*NE_)             // 33554432 (spk passthrough, fp32)

typedef __attribute__((ext_vector_type(8))) short short8;   // 8 bf16 = 4 VGPRs
typedef __attribute__((ext_vector_type(4))) float f32x4;    // clang ext-vector
typedef __attribute__((ext_vector_type(4))) short short4v;

// ---- ws layout (bytes) ----
// [0, 131072)            : Wb bf16 (256*256)
// [131072, +3145728)     : ctx bits: [t'<12][b][c][8 words] uint32
// [3276800, +4194304)    : spk bits: [t<16][b][c][8 words] uint32
// [7471104, +1536)       : s_pos[384], s_neg[384] f32 accumulators
// NOTE hw bit-order inside the 8 words is PERMUTED (bit i of word-pair j
// means hw=4i+j); consistent between spkw and ctxw, and k_gemm only ever
// pairs equal (word,bit) coords of the two, so the permutation cancels.
#define WS_WB   0
#define WS_CTX  131072
#define WS_SPK  3276800
#define WS_ACC  7471104

// ---------------- setup: W fp32 -> bf16 (x4), zero accumulators -----------
__global__ void k_setup(const f32x4* __restrict__ W4,
                        short4v* __restrict__ Wb4,
                        float* __restrict__ acc) {
    int i = blockIdx.x*256 + threadIdx.x;         // 64 blocks -> 16384 float4s
    f32x4 v = W4[i];
    short4v s;
    #pragma unroll
    for (int j = 0; j < 4; ++j) {
        __hip_bfloat16 h = __float2bfloat16(v[j]);
        s[j] = *(short*)&h;
    }
    Wb4[i] = s;
    if (i < 768) acc[i] = 0.f;
}

// ---------------- scan: float4 passthrough + LIF scan + bit-pack ---------
// One wave = one (b,c) row (256 hw). Thread owns float4 = hw 4*lane..+3.
__global__ __launch_bounds__(256)
void k_scan(const f32x4* __restrict__ spk,
            f32x4* __restrict__ out,
            unsigned* __restrict__ ctxw,
            unsigned* __restrict__ spkw) {
    int wave = (blockIdx.x*256 + threadIdx.x) >> 6;   // row id 0..8191 (=b*256+c)
    int lane = threadIdx.x & 63;
    long base = (long)wave*64 + lane;                 // float4 index
    float m0=0.f, m1=0.f, m2=0.f, m3=0.f;
    #pragma unroll
    for (int t = 0; t < T_; ++t) {
        long o = (long)t*(NE_/4) + base;
        f32x4 v = __builtin_nontemporal_load(&spk[o]);
        __builtin_nontemporal_store(v, &out[o]);      // exact passthrough
        if (t >= 4) {   // spk bits only needed for t in [4,16)
            unsigned long long s0 = __ballot(v.x != 0.f);
            unsigned long long s1 = __ballot(v.y != 0.f);
            unsigned long long s2 = __ballot(v.z != 0.f);
            unsigned long long s3 = __ballot(v.w != 0.f);
            if (lane < 8) {
                unsigned long long m = (lane<2)?s0 : (lane<4)?s1 : (lane<6)?s2 : s3;
                unsigned w = (lane & 1) ? (unsigned)(m>>32) : (unsigned)m;
                spkw[((long)t*8192 + wave)*8 + lane] = w;
            }
        }
        float r0 = (m0-1.f>0.f)?1.f:0.f; m0 = 0.5f*m0 + v.x - r0;
        float r1 = (m1-1.f>0.f)?1.f:0.f; m1 = 0.5f*m1 + v.y - r1;
        float r2 = (m2-1.f>0.f)?1.f:0.f; m2 = 0.5f*m2 + v.z - r2;
        float r3 = (m3-1.f>0.f)?1.f:0.f; m3 = 0.5f*m3 + v.w - r3;
        if (t < TP_) {
            unsigned long long c0 = __ballot(m0-1.f>0.f);
            unsigned long long c1 = __ballot(m1-1.f>0.f);
            unsigned long long c2 = __ballot(m2-1.f>0.f);
            unsigned long long c3 = __ballot(m3-1.f>0.f);
            if (lane >= 8 && lane < 16) {
                int j = lane - 8;
                unsigned long long m = (j<2)?c0 : (j<4)?c1 : (j<6)?c2 : c3;
                unsigned w = (j & 1) ? (unsigned)(m>>32) : (unsigned)m;
                ctxw[((long)t*8192 + wave)*8 + j] = w;
            }
        }
    }
}

// ---------------- gemm: X = W @ S per (t,b,hwtile); mask-reduce vs ctx ----
// S comes bit-packed; expand to bf16 in LDS once, then barrier-free K loop.
__global__ __launch_bounds__(256, 2)
void k_gemm(const unsigned short* __restrict__ Wb,   // bf16 weight (o,c), in ws
            const unsigned* __restrict__ spkw,       // packed S bits
            const unsigned* __restrict__ ctxw,
            const int* __restrict__ ridx,
            float* __restrict__ spos, float* __restrict__ sneg) {
    int blk  = blockIdx.x;
    int pair = blk >> 2;                 // 0..383
    int jblk = blk & 3;
    int t  = 4 + (pair >> 5);            // 4..15
    int b  = pair & 31;
    int tp = t - 4;
    int hwbase = jblk * 64;

    int wv   = threadIdx.x >> 6;         // wave 0..3 -> o in [64*wv, 64*wv+64)
    int lane = threadIdx.x & 63;
    int quad = lane >> 4;
    int n    = lane & 15;

    // full S tile transposed: [hw 64][c 256+8pad] bf16 (rows 16B-aligned)
    __shared__ __align__(16) unsigned short Ssl[64*264];
    __shared__ __align__(16) unsigned Sw2[512];       // [wi 2][c 256]
    __shared__ unsigned ctxp[512], ctxn[512];
    __shared__ float red[8];

    // ---- load packed words + ctx masks (overlapped, one barrier) ----
    {
        int c = threadIdx.x;             // 0..255
        const uint2 w = *(const uint2*)&spkw[((long)t*8192 + b*256 + c)*8 + (hwbase>>5)];
        Sw2[c]       = w.x;
        Sw2[256 + c] = w.y;
    }
    int bneg = 0;
    #pragma unroll
    for (int i = 0; i < 32; ++i) if (ridx[i] == b) bneg = i;  // permutation inverse
    for (int i = threadIdx.x; i < 512; i += 256) {
        int o = i >> 1, w = i & 1;
        int hwword = (hwbase >> 5) + w;
        ctxp[i] = ctxw[((tp*B_ + b   )*C_ + o)*8 + hwword];
        ctxn[i] = ctxw[((tp*B_ + bneg)*C_ + o)*8 + hwword];
    }
    __syncthreads();

    // ---- expand bits -> bf16 tile ----
    #pragma unroll
    for (int p = 0; p < 8; ++p) {
        int v  = threadIdx.x + p*256;
        int hw = v >> 5;                 // 0..63
        int c0 = (v & 31)*8;             // 0..248
        int wi = hw >> 5, bit = hw & 31;
        uint4 wa = *(const uint4*)&Sw2[wi*256 + c0];
        uint4 wb2 = *(const uint4*)&Sw2[wi*256 + c0 + 4];
        unsigned ww[8] = {wa.x, wa.y, wa.z, wa.w, wb2.x, wb2.y, wb2.z, wb2.w};
        short8 s;
        #pragma unroll
        for (int j = 0; j < 8; ++j)
            s[j] = (short)(((ww[j] >> bit) & 1u) ? 0x3F80 : 0);
        *(short8*)&Ssl[hw*264 + c0] = s;
    }
    __syncthreads();

    // ---- barrier-free K loop: 8 x (4 ds_read_b128 + 4 dwordx4 + 16 MFMA) ----
    f32x4 acc[4][4] = {};
    #pragma unroll
    for (int kc = 0; kc < 256; kc += 32) {
        short8 bfr[4], afr[4];
        #pragma unroll
        for (int jt = 0; jt < 4; ++jt)
            bfr[jt] = *(const short8*)&Ssl[(jt*16 + n)*264 + kc + quad*8];
        #pragma unroll
        for (int ot = 0; ot < 4; ++ot) {
            int o = wv*64 + ot*16 + n;
            afr[ot] = *(const short8*)&Wb[o*256 + kc + quad*8];  // L2-resident
        }
        #pragma unroll
        for (int ot = 0; ot < 4; ++ot)
            #pragma unroll
            for (int jt = 0; jt < 4; ++jt)
                acc[ot][jt] = __builtin_amdgcn_mfma_f32_16x16x32_bf16(
                                  afr[ot], bfr[jt], acc[ot][jt], 0, 0, 0);
    }

    // ---- masked reduction vs ctx bits ----
    float P = 0.f, Nn = 0.f;
    #pragma unroll
    for (int ot = 0; ot < 4; ++ot)
        #pragma unroll
        for (int jt = 0; jt < 4; ++jt) {
            int hwl = jt*16 + n;
            int w = hwl >> 5, bit = hwl & 31;
            #pragma unroll
            for (int r = 0; r < 4; ++r) {
                int o = wv*64 + ot*16 + quad*4 + r;   // C/D: row=quad*4+r, col=n
                float x = acc[ot][jt][r];
                if ((ctxp[o*2 + w] >> bit) & 1) P  += x;
                if ((ctxn[o*2 + w] >> bit) & 1) Nn += x;
            }
        }
    for (int off = 32; off; off >>= 1) {
        P  += __shfl_down(P,  off);
        Nn += __shfl_down(Nn, off);
    }
    if (lane == 0) { red[wv] = P; red[4 + wv] = Nn; }
    __syncthreads();
    if (threadIdx.x == 0)
        atomicAdd(&spos[tp*32 + b],    red[0]+red[1]+red[2]+red[3]);
    if (threadIdx.x == 1)
        atomicAdd(&sneg[tp*32 + bneg], red[4]+red[5]+red[6]+red[7]);
}

// ---------------- final: scores -> logs -> loss, write fp32 tail ---------
__global__ void k_final(const float* __restrict__ spos,
                        const float* __restrict__ sneg,
                        float* __restrict__ out) {
    __shared__ float lsp_s[384], sn_s[384], lsn_s[12];
    int tid = threadIdx.x;
    if (tid < 384) {
        float mp = spos[tid] * (1.f/65536.f);
        lsp_s[tid] = logf(expf(mp) + 1e-4f);
        float mn = sneg[tid] * (1.f/65536.f);
        sn_s[tid] = expf(mn) + 1e-4f;
    }
    __syncthreads();
    if (tid < 12) {
        float s = 0.f;
        for (int b = 0; b < 32; ++b) s += sn_s[tid*32 + b];
        float lsn = logf(s);
        lsn_s[tid] = lsn;
        out[NOUT0 + 1 + 384 + tid] = lsn;
    }
    __syncthreads();
    if (tid < 384) out[NOUT0 + 1 + tid] = lsp_s[tid];
    if (tid == 0) {
        float L = 0.f;
        for (int t = 0; t < 12; ++t)
            for (int b = 0; b < 32; ++b)
                L += lsn_s[t] - lsp_s[t*32 + b];
        out[NOUT0] = L * (1.f/384.f);
    }
}

extern "C" void kernel_launch(void* const* d_in, const int* in_sizes, int n_in,
                              void* d_out, int out_size, void* d_ws, size_t ws_size,
                              hipStream_t stream) {
    const float* spk  = (const float*)d_in[0];
    // d_in[1] (mem_rec) is unused by the reference
    const float* W    = (const float*)d_in[2];
    const int*   ridx = (const int*)d_in[3];
    float* out = (float*)d_out;

    char* ws = (char*)d_ws;
    unsigned short* Wb   = (unsigned short*)(ws + WS_WB);
    unsigned*       ctxw = (unsigned*)(ws + WS_CTX);
    unsigned*       spkw = (unsigned*)(ws + WS_SPK);
    float*          acc  = (float*)(ws + WS_ACC);
    float*          spos = acc;          // 384
    float*          sneg = acc + 384;    // 384

    k_setup<<<64, 256, 0, stream>>>((const f32x4*)W, (short4v*)Wb, acc);
    k_scan <<<2048, 256, 0, stream>>>((const f32x4*)spk, (f32x4*)out, ctxw, spkw);
    k_gemm <<<1536, 256, 0, stream>>>(Wb, spkw, ctxw, ridx, spos, sneg);
    k_final<<<1, 384, 0, stream>>>(spos, sneg, out);
}